// Round 2
// baseline (743.789 us; speedup 1.0000x reference)
//
#include <hip/hip_runtime.h>

#define IN_C 64
#define OUT_C 128
#define HID 32
#define KNB 16
#define NEG 0.1f

// leaky(v, s) with 0<s<1 == max(v, s*v): v>=0 -> v, v<0 -> s*v. Branch-free.
__device__ __forceinline__ float leaky(float v, float s) { return fmaxf(v, s * v); }

// Kernel 1: h = leaky(x @ W_in + b_in, 0.1)   [P,64] -> [P,32]
// One lane per point: all weight addresses wave-uniform -> s_load broadcasts.
__global__ __launch_bounds__(256) void hid_kernel(
    const float* __restrict__ x, const float* __restrict__ Win,
    const float* __restrict__ bin, float* __restrict__ h, int P)
{
    int p = blockIdx.x * blockDim.x + threadIdx.x;
    if (p >= P) return;

    float xr[IN_C];
    const float4* x4 = (const float4*)(x + (long)p * IN_C);
    #pragma unroll
    for (int i = 0; i < IN_C / 4; ++i) {
        float4 v = x4[i];
        xr[4 * i + 0] = v.x; xr[4 * i + 1] = v.y;
        xr[4 * i + 2] = v.z; xr[4 * i + 3] = v.w;
    }

    float acc[HID];
    #pragma unroll
    for (int c = 0; c < HID; ++c) acc[c] = bin[c];

    #pragma unroll 8
    for (int k = 0; k < IN_C; ++k) {
        float xv = xr[k];
        #pragma unroll
        for (int c = 0; c < HID; ++c) acc[c] = fmaf(xv, Win[k * HID + c], acc[c]);
    }

    float4* h4 = (float4*)(h + (long)p * HID);
    #pragma unroll
    for (int c2 = 0; c2 < HID / 4; ++c2) {
        float4 v;
        v.x = leaky(acc[4 * c2 + 0], NEG);
        v.y = leaky(acc[4 * c2 + 1], NEG);
        v.z = leaky(acc[4 * c2 + 2], NEG);
        v.w = leaky(acc[4 * c2 + 3], NEG);
        h4[c2] = v;
    }
}

// Kernel 2: wave-role split. Block = 4 waves = 128 points.
//   wave w: point group pg=(w&1) (64 points), edge half=(w>>1) (8 edges).
//   Phase A: conv partial over own 8 edges (weights wave-uniform -> s_load).
//   LDS reduce of conv across the two halves.
//   Phase B: GEMV; wave w computes out channels [64*(w>>1), +64) -> uniform.
__global__ __launch_bounds__(256, 4) void point_kernel(
    const float* __restrict__ x, const float* __restrict__ pos,
    const int* __restrict__ nbr, const float* __restrict__ h,
    const float* __restrict__ Wa, const float* __restrict__ ba,
    const float* __restrict__ Wb, const float* __restrict__ bb,
    const float* __restrict__ Wout, const float* __restrict__ bout,
    const float* __restrict__ Wsc, const float* __restrict__ bsc,
    float* __restrict__ out, int N, int P)
{
    __shared__ float cbuf[128][HID + 1];   // stride 33 words -> conflict-free

    int lane = threadIdx.x & 63;
    int w    = threadIdx.x >> 6;
    int pg   = w & 1;       // point group within block
    int half = w >> 1;      // edge half / output half
    int pib  = pg * 64 + lane;

    int p = blockIdx.x * 128 + pib;
    if (p >= P) p = P - 1;                 // clamp (keeps barriers uniform)
    long pbase = (p >= N) ? (long)N : 0;   // per-batch index base

    float px = pos[3L * p + 0];
    float py = pos[3L * p + 1];
    float pz = pos[3L * p + 2];

    float conv[HID];
    #pragma unroll
    for (int c = 0; c < HID; ++c) conv[c] = 0.f;

    // ---- Phase A: 8 edges ----
    const int* nrow = nbr + (long)p * KNB + half * 8;
    int  j = nrow[0];
    long q = pbase + j;
    float qx = pos[3 * q + 0], qy = pos[3 * q + 1], qz = pos[3 * q + 2];

    #pragma unroll 1
    for (int e = 0; e < 8; ++e) {
        // issue gathered-h loads early; consumed only after the 32x32 GEMM
        const float4* h4 = (const float4*)(h + q * HID);
        float4 hg0 = h4[0], hg1 = h4[1], hg2 = h4[2], hg3 = h4[3];
        float4 hg4 = h4[4], hg5 = h4[5], hg6 = h4[6], hg7 = h4[7];

        float rx = px - qx, ry = py - qy, rz = pz - qz;

        // prefetch next edge's index + neighbor pos
        if (e < 7) {
            j = nrow[e + 1];
            q = pbase + j;
            qx = pos[3 * q + 0]; qy = pos[3 * q + 1]; qz = pos[3 * q + 2];
        }

        float t[HID];
        #pragma unroll
        for (int c = 0; c < HID; ++c) {
            float v = fmaf(rx, Wa[c], fmaf(ry, Wa[HID + c], fmaf(rz, Wa[2 * HID + c], ba[c])));
            t[c] = leaky(v, NEG);
        }

        float hgv[HID] = {
            hg0.x, hg0.y, hg0.z, hg0.w,  hg1.x, hg1.y, hg1.z, hg1.w,
            hg2.x, hg2.y, hg2.z, hg2.w,  hg3.x, hg3.y, hg3.z, hg3.w,
            hg4.x, hg4.y, hg4.z, hg4.w,  hg5.x, hg5.y, hg5.z, hg5.w,
            hg6.x, hg6.y, hg6.z, hg6.w,  hg7.x, hg7.y, hg7.z, hg7.w };

        #pragma unroll
        for (int c = 0; c < HID; ++c) {
            float wv = bb[c];
            #pragma unroll
            for (int jj = 0; jj < HID; ++jj) wv = fmaf(t[jj], Wb[jj * HID + c], wv);
            conv[c] = fmaf(wv, hgv[c], conv[c]);
        }
    }

    // ---- reduce conv across edge halves through LDS ----
    if (half) {
        #pragma unroll
        for (int c = 0; c < HID; ++c) cbuf[pib][c] = conv[c];
    }
    __syncthreads();
    if (!half) {
        #pragma unroll
        for (int c = 0; c < HID; ++c) {
            conv[c] += cbuf[pib][c];
            cbuf[pib][c] = conv[c];
        }
    }
    __syncthreads();

    // ---- Phase B: GEMV, outputs [half*64, half*64+64) ----
    float cv[HID];
    if (half) {
        #pragma unroll
        for (int c = 0; c < HID; ++c) cv[c] = cbuf[pib][c];
    } else {
        #pragma unroll
        for (int c = 0; c < HID; ++c) cv[c] = conv[c];
    }

    float xr[IN_C];
    const float4* x4 = (const float4*)(x + (long)p * IN_C);
    #pragma unroll
    for (int i = 0; i < IN_C / 4; ++i) {
        float4 v = x4[i];
        xr[4 * i + 0] = v.x; xr[4 * i + 1] = v.y;
        xr[4 * i + 2] = v.z; xr[4 * i + 3] = v.w;
    }

    int obase = half * 64;
    float* op = out + (long)p * OUT_C;

    #pragma unroll 1
    for (int chunk = 0; chunk < 8; ++chunk) {
        int o0 = obase + chunk * 8;
        float a[8];
        #pragma unroll
        for (int l = 0; l < 8; ++l) a[l] = bout[o0 + l] + bsc[o0 + l];
        #pragma unroll
        for (int c = 0; c < HID; ++c) {
            float v = cv[c];
            const float* wr = Wout + c * OUT_C + o0;
            #pragma unroll
            for (int l = 0; l < 8; ++l) a[l] = fmaf(v, wr[l], a[l]);
        }
        #pragma unroll
        for (int k = 0; k < IN_C; ++k) {
            float v = xr[k];
            const float* wr = Wsc + k * OUT_C + o0;
            #pragma unroll
            for (int l = 0; l < 8; ++l) a[l] = fmaf(v, wr[l], a[l]);
        }
        float4 v0, v1;
        v0.x = leaky(a[0], 0.01f); v0.y = leaky(a[1], 0.01f);
        v0.z = leaky(a[2], 0.01f); v0.w = leaky(a[3], 0.01f);
        v1.x = leaky(a[4], 0.01f); v1.y = leaky(a[5], 0.01f);
        v1.z = leaky(a[6], 0.01f); v1.w = leaky(a[7], 0.01f);
        *(float4*)(op + o0 + 0) = v0;
        *(float4*)(op + o0 + 4) = v1;
    }
}

extern "C" void kernel_launch(void* const* d_in, const int* in_sizes, int n_in,
                              void* d_out, int out_size, void* d_ws, size_t ws_size,
                              hipStream_t stream) {
    const float* x    = (const float*)d_in[0];
    const float* pos  = (const float*)d_in[1];
    const int*   nbr  = (const int*)d_in[2];
    const float* Win  = (const float*)d_in[3];
    const float* bin  = (const float*)d_in[4];
    const float* Wa   = (const float*)d_in[5];
    const float* ba   = (const float*)d_in[6];
    const float* Wb   = (const float*)d_in[7];
    const float* bb   = (const float*)d_in[8];
    const float* Wout = (const float*)d_in[9];
    const float* bout = (const float*)d_in[10];
    const float* Wsc  = (const float*)d_in[11];
    const float* bsc  = (const float*)d_in[12];
    float* out = (float*)d_out;

    int P = in_sizes[0] / IN_C;   // B*N
    int N = P / 2;                // B = 2 per reference
    float* h = (float*)d_ws;      // P*HID floats

    hid_kernel<<<(P + 255) / 256, 256, 0, stream>>>(x, Win, bin, h, P);
    point_kernel<<<(P + 127) / 128, 256, 0, stream>>>(
        x, pos, nbr, h, Wa, ba, Wb, bb, Wout, bout, Wsc, bsc, out, N, P);
}